// Round 10
// baseline (782.219 us; speedup 1.0000x reference)
//
#include <hip/hip_runtime.h>
#include <math.h>
#include <stdint.h>

// Problem constants
#define NTOT   65536
#define NPG    1024
#define KNN    8
#define HDIM   128
#define XSTR   33     // x row stride (32 feat + 1 kf)
#define NEG    0.2f

typedef _Float16 h2 __attribute__((ext_vector_type(2)));
typedef _Float16 h8 __attribute__((ext_vector_type(8)));   // f16x8 MFMA frag
typedef short bf16x8 __attribute__((ext_vector_type(8)));
typedef float f32x4 __attribute__((ext_vector_type(4)));
typedef unsigned short u16;
typedef unsigned int u32;

__device__ __forceinline__ u16 f2bf(float f) {  // RNE float->bf16
  const u32 u = __builtin_bit_cast(u32, f);
  return (u16)((u + 0x7FFFu + ((u >> 16) & 1u)) >> 16);
}
__device__ __forceinline__ float bf2f(u16 h) {
  return __builtin_bit_cast(float, ((u32)h) << 16);
}
__device__ __forceinline__ void bf8_to_f(const u16* __restrict__ p, float* f) {
  const uint4 v = *reinterpret_cast<const uint4*>(p);
  const u32 w[4] = {v.x, v.y, v.z, v.w};
#pragma unroll
  for (int i = 0; i < 4; ++i) {
    f[2 * i]     = bf2f((u16)(w[i] & 0xffffu));
    f[2 * i + 1] = bf2f((u16)(w[i] >> 16));
  }
}

// ---------------------------------------------------------------------------
// K0: xh = relu(feat @ w0 + b0) -> split bf16 (hi, lo); sq[n] = sum(xh^2) fp32
// ---------------------------------------------------------------------------
__global__ __launch_bounds__(256) void k_embed(const float* __restrict__ x,
                                               const float* __restrict__ w0,
                                               const float* __restrict__ b0,
                                               u16* __restrict__ xh_hi,
                                               u16* __restrict__ xh_lo,
                                               float* __restrict__ sq) {
  __shared__ float w0s[32 * HDIM];
  __shared__ float fs[2][32];
  __shared__ float red[256];
  const int tid = threadIdx.x;
  for (int i = tid; i < 32 * HDIM; i += 256) w0s[i] = w0[i];
  const int h = tid & 127;
  const int nl = tid >> 7;
  const float bias = b0[h];
  for (int it = 0; it < 16; ++it) {
    const int n = blockIdx.x * 32 + it * 2 + nl;
    __syncthreads();
    if (tid < 64) {
      const int r = tid >> 5, f = tid & 31;
      fs[r][f] = x[(size_t)(blockIdx.x * 32 + it * 2 + r) * XSTR + f];
    }
    __syncthreads();
    float acc = bias;
#pragma unroll
    for (int f = 0; f < 32; ++f) acc = fmaf(fs[nl][f], w0s[f * HDIM + h], acc);
    acc = fmaxf(acc, 0.f);
    const u16 hh = f2bf(acc);
    xh_hi[(size_t)n * HDIM + h] = hh;
    xh_lo[(size_t)n * HDIM + h] = f2bf(acc - bf2f(hh));
    red[tid] = acc * acc;
    __syncthreads();
    for (int s = 64; s > 0; s >>= 1) {
      if ((tid & 127) < s) red[tid] += red[tid + s];
      __syncthreads();
    }
    if ((tid & 127) == 0) sq[n] = red[tid];
  }
}

// ---------------------------------------------------------------------------
// K-prep: b 0..7: transpose node-GEMM weight blocks to bf16 [n][k].
//          b 8..9: transpose mw2 (layer 1/2) to f16 [h][k].
// grid 10 x 256.
// ---------------------------------------------------------------------------
__global__ __launch_bounds__(256) void k_prep(const float* __restrict__ m1,
                                              const float* __restrict__ g1,
                                              const float* __restrict__ m2,
                                              const float* __restrict__ g2,
                                              const float* __restrict__ w2a,
                                              const float* __restrict__ w2b,
                                              u16* __restrict__ Wt) {
  const int b = blockIdx.x;
  const int t = threadIdx.x;
  const int n = t >> 1, k0 = (t & 1) * 64;
  u16* dst = Wt + (size_t)b * 128 * 128;
  if (b < 8) {
    const int layer = b >> 2, which = b & 3;
    const float* src = (layer == 0) ? ((which < 2) ? m1 : g1)
                                    : ((which < 2) ? m2 : g2);
    src += (size_t)(which & 1) * 128 * HDIM;
    for (int kk = 0; kk < 64; kk += 2) {
      const float f0 = src[(size_t)(k0 + kk) * HDIM + n];
      const float f1 = src[(size_t)(k0 + kk + 1) * HDIM + n];
      const u32 pk = (u32)f2bf(f0) | ((u32)f2bf(f1) << 16);
      *reinterpret_cast<u32*>(&dst[(size_t)n * 128 + k0 + kk]) = pk;
    }
  } else {
    const float* src = (b == 8) ? w2a : w2b;
    for (int kk = 0; kk < 64; kk += 2) {
      const float f0 = src[(size_t)(k0 + kk) * HDIM + n];
      const float f1 = src[(size_t)(k0 + kk + 1) * HDIM + n];
      const u16 h0 = __builtin_bit_cast(u16, (_Float16)f0);
      const u16 h1 = __builtin_bit_cast(u16, (_Float16)f1);
      const u32 pk = (u32)h0 | ((u32)h1 << 16);
      *reinterpret_cast<u32*>(&dst[(size_t)n * 128 + k0 + kk]) = pk;
    }
  }
}

// ---------------------------------------------------------------------------
// K1: per-graph kNN via split-bf16 MFMA (hi*hi + hi*lo + lo*hi, fp32 accum).
// grid 512 (64 graphs x 8 row-blocks of 128), 256 threads = 4 waves.
// ---------------------------------------------------------------------------
__global__ __launch_bounds__(256) void k_knn(const u16* __restrict__ xh_hi,
                                             const u16* __restrict__ xh_lo,
                                             const float* __restrict__ sq,
                                             int* __restrict__ nbr) {
  __shared__ __align__(16) u16 BsH[32 * 128];
  __shared__ __align__(16) u16 BsL[32 * 128];
  __shared__ __align__(16) float Ds[128 * 33];
  __shared__ float sqs[32];
  const int tid = threadIdx.x;
  const int wave = tid >> 6, lane = tid & 63;
  const int fr = lane & 15, fg = lane >> 4;
  const int g = blockIdx.x >> 3;
  const int n0 = (blockIdx.x & 7) * 128;
  const int gbase = g * NPG;

  bf16x8 aH[2][4], aL[2][4];
#pragma unroll
  for (int mt = 0; mt < 2; ++mt)
#pragma unroll
    for (int kt = 0; kt < 4; ++kt) {
      const size_t off =
          (size_t)(gbase + n0 + wave * 32 + mt * 16 + fr) * HDIM + kt * 32 + fg * 8;
      aH[mt][kt] = *reinterpret_cast<const bf16x8*>(&xh_hi[off]);
      aL[mt][kt] = *reinterpret_cast<const bf16x8*>(&xh_lo[off]);
    }

  const int srow = tid >> 1, shalf = tid & 1;
  const int nglob = gbase + n0 + srow;
  float bd[8];
  int bi[8];
#pragma unroll
  for (int i = 0; i < 8; ++i) { bd[i] = 1e30f; bi[i] = 0; }

  char* BsHc = reinterpret_cast<char*>(BsH);
  char* BsLc = reinterpret_cast<char*>(BsL);

  for (int ct = 0; ct < 32; ++ct) {
    const int m0 = gbase + ct * 32;
    __syncthreads();
    if (tid < 32) sqs[tid] = sq[m0 + tid];
    {
      const int col = tid >> 3, kc = (tid & 7) * 16;
      const size_t off = (size_t)(m0 + col) * HDIM + kc;
      const uint4 h0 = *reinterpret_cast<const uint4*>(&xh_hi[off]);
      const uint4 h1 = *reinterpret_cast<const uint4*>(&xh_hi[off + 8]);
      const uint4 l0 = *reinterpret_cast<const uint4*>(&xh_lo[off]);
      const uint4 l1 = *reinterpret_cast<const uint4*>(&xh_lo[off + 8]);
      const int base = col * 256, sw = (col & 7) << 4;
      const int kb = kc * 2;
      *reinterpret_cast<uint4*>(BsHc + base + ((kb) ^ sw)) = h0;
      *reinterpret_cast<uint4*>(BsHc + base + ((kb + 16) ^ sw)) = h1;
      *reinterpret_cast<uint4*>(BsLc + base + ((kb) ^ sw)) = l0;
      *reinterpret_cast<uint4*>(BsLc + base + ((kb + 16) ^ sw)) = l1;
    }
    __syncthreads();
    f32x4 acc[2][2];
#pragma unroll
    for (int mt = 0; mt < 2; ++mt)
#pragma unroll
      for (int nt = 0; nt < 2; ++nt) acc[mt][nt] = (f32x4){0.f, 0.f, 0.f, 0.f};
#pragma unroll
    for (int nt = 0; nt < 2; ++nt) {
      bf16x8 bH[4], bL[4];
      const int col = nt * 16 + fr;
      const int base = col * 256, sw = (col & 7) << 4;
#pragma unroll
      for (int kt = 0; kt < 4; ++kt) {
        const int kb = (kt * 32 + fg * 8) * 2;
        bH[kt] = *reinterpret_cast<const bf16x8*>(BsHc + base + (kb ^ sw));
        bL[kt] = *reinterpret_cast<const bf16x8*>(BsLc + base + (kb ^ sw));
      }
#pragma unroll
      for (int mt = 0; mt < 2; ++mt)
#pragma unroll
        for (int kt = 0; kt < 4; ++kt) {
          acc[mt][nt] = __builtin_amdgcn_mfma_f32_16x16x32_bf16(
              aH[mt][kt], bH[kt], acc[mt][nt], 0, 0, 0);
          acc[mt][nt] = __builtin_amdgcn_mfma_f32_16x16x32_bf16(
              aH[mt][kt], bL[kt], acc[mt][nt], 0, 0, 0);
          acc[mt][nt] = __builtin_amdgcn_mfma_f32_16x16x32_bf16(
              aL[mt][kt], bH[kt], acc[mt][nt], 0, 0, 0);
        }
    }
#pragma unroll
    for (int mt = 0; mt < 2; ++mt)
#pragma unroll
      for (int nt = 0; nt < 2; ++nt)
#pragma unroll
        for (int r = 0; r < 4; ++r)
          Ds[(wave * 32 + mt * 16 + fg * 4 + r) * 33 + nt * 16 + fr] =
              acc[mt][nt][r];
    __syncthreads();
#pragma unroll
    for (int c2 = 0; c2 < 16; ++c2) {
      const int c = shalf * 16 + c2;
      const int m = m0 + c;
      const float d = sqs[c] - 2.f * Ds[srow * 33 + c];
      if ((m != nglob) && (d < bd[7])) {
        bd[7] = d; bi[7] = m;
#pragma unroll
        for (int q = 7; q > 0; --q) {
          if (bd[q] < bd[q - 1]) {
            const float td = bd[q]; bd[q] = bd[q - 1]; bd[q - 1] = td;
            const int ti = bi[q]; bi[q] = bi[q - 1]; bi[q - 1] = ti;
          }
        }
      }
    }
  }
  __syncthreads();
  float* mdist = Ds;
  int* midx = reinterpret_cast<int*>(BsH);
#pragma unroll
  for (int i = 0; i < 8; ++i) { mdist[tid * 8 + i] = bd[i]; midx[tid * 8 + i] = bi[i]; }
  __syncthreads();
  if (shalf == 0) {
    const float* dA = &mdist[(srow * 2) * 8];
    const float* dB = &mdist[(srow * 2 + 1) * 8];
    const int* iA = &midx[(srow * 2) * 8];
    const int* iB = &midx[(srow * 2 + 1) * 8];
    int pa = 0, pb = 0;
    int* outp = &nbr[(size_t)nglob * KNN];
#pragma unroll
    for (int i = 0; i < 8; ++i) {
      const float da = dA[pa], db = dB[pb];
      const bool takeA = (da < db) || ((da == db) && (iA[pa] < iB[pb]));
      outp[i] = takeA ? iA[pa] : iB[pb];
      if (takeA) ++pa; else ++pb;
    }
  }
}

// ---------------------------------------------------------------------------
// K2: node GEMMs via bf16 MFMA. out = xin_b @ W (+bias) -> bf16.
// ---------------------------------------------------------------------------
__global__ __launch_bounds__(256) void k_ng(const u16* __restrict__ xin_b,
                                            const u16* __restrict__ WtL,
                                            const float* __restrict__ mb1,
                                            const float* __restrict__ gb,
                                            u16* __restrict__ a1,
                                            u16* __restrict__ a2,
                                            u16* __restrict__ uu,
                                            u16* __restrict__ vv) {
  const int tid = threadIdx.x;
  const int wave = tid >> 6, lane = tid & 63;
  const int fr = lane & 15, fg = lane >> 4;
  const int n0 = blockIdx.x * 128;
  const int cb = blockIdx.y;
  const u16* W = WtL + (size_t)cb * 128 * 128;
  const float* bias = (cb == 0) ? mb1 : (cb == 2) ? gb : nullptr;
  u16* outp = (cb == 0) ? a1 : (cb == 1) ? a2 : (cb == 2) ? uu : vv;

  bf16x8 afr[2][4];
#pragma unroll
  for (int mt = 0; mt < 2; ++mt)
#pragma unroll
    for (int kt = 0; kt < 4; ++kt)
      afr[mt][kt] = *reinterpret_cast<const bf16x8*>(
          &xin_b[(size_t)(n0 + wave * 32 + mt * 16 + fr) * HDIM + kt * 32 + fg * 8]);

#pragma unroll
  for (int nt = 0; nt < 8; ++nt) {
    const int col = nt * 16 + fr;
    bf16x8 bfr[4];
#pragma unroll
    for (int kt = 0; kt < 4; ++kt)
      bfr[kt] = *reinterpret_cast<const bf16x8*>(&W[(size_t)col * 128 + kt * 32 + fg * 8]);
    const float bv = bias ? bias[col] : 0.f;
#pragma unroll
    for (int mt = 0; mt < 2; ++mt) {
      f32x4 acc = (f32x4){0.f, 0.f, 0.f, 0.f};
#pragma unroll
      for (int kt = 0; kt < 4; ++kt)
        acc = __builtin_amdgcn_mfma_f32_16x16x32_bf16(afr[mt][kt], bfr[kt], acc, 0, 0, 0);
      const int rbase = n0 + wave * 32 + mt * 16 + fg * 4;
#pragma unroll
      for (int r = 0; r < 4; ++r)
        outp[(size_t)(rbase + r) * HDIM + col] = f2bf(acc[r] + bv);
    }
  }
}

// ---------------------------------------------------------------------------
// K3: fused highway edge conv, MFMA edition, spill-free.
// mt-outer loop: only 4 E-fragments (16 VGPRs) live at a time; B-fragments
// re-read per mt from L2-hot mw2t. M staged f16 in LDS (34.8 KB). Plain
// __launch_bounds__(256) — no min-waves hint (round 9 showed (256,4) forces
// a 64-VGPR clamp + scratch spills: WRITE_SIZE 16->224 MB).
// grid 4096 x 256 (4 waves).
// ---------------------------------------------------------------------------
__global__ __launch_bounds__(256) void k_conv(const u16* __restrict__ xin,
                                              const int* __restrict__ nbr,
                                              const float* __restrict__ xraw,
                                              const u16* __restrict__ a1,
                                              const u16* __restrict__ a2,
                                              const u16* __restrict__ uu,
                                              const u16* __restrict__ vv,
                                              const float* __restrict__ mw1,
                                              const u16* __restrict__ mw2t,  // f16 [h][k]
                                              const float* __restrict__ mb2,
                                              const float* __restrict__ gw,
                                              u16* __restrict__ xout) {
  __shared__ __align__(16) u16 Msh[128 * 136];   // f16 M, 34816 B
  __shared__ int jn[128];
  __shared__ float fdv[128];
  __shared__ float w1rs[HDIM];
  __shared__ float gwrs[HDIM];
  const int tid = threadIdx.x;
  const int i0 = blockIdx.x * 16;

  if (tid < 128) {
    w1rs[tid] = mw1[256 * HDIM + tid];
    gwrs[tid] = gw[256 * HDIM + tid];
    const int i = i0 + (tid >> 3);
    const int j = nbr[(size_t)i * KNN + (tid & 7)];
    jn[tid] = j;
    fdv[tid] = xraw[(size_t)i * XSTR + 32] - xraw[(size_t)j * XSTR + 32];
  }
  __syncthreads();

  const int wave = tid >> 6, lane = tid & 63;
  const int fr = lane & 15, fg = lane >> 4;

  // GEMM with mt as the OUTER loop: E-fragments for one 16-row block only.
#pragma unroll
  for (int mt = 0; mt < 2; ++mt) {
    const int e = wave * 32 + mt * 16 + fr;
    const int inode = i0 + (e >> 3);
    const int j = jn[e];
    const float fd = fdv[e];
    h8 ef[4];
#pragma unroll
    for (int kt = 0; kt < 4; ++kt) {
      const int k0 = kt * 32 + fg * 8;
      float fa[8], fb[8];
      bf8_to_f(&a1[(size_t)inode * HDIM + k0], fa);
      bf8_to_f(&a2[(size_t)j * HDIM + k0], fb);
      h8 t;
#pragma unroll
      for (int q = 0; q < 8; ++q)
        t[q] = (_Float16)fmaxf(fa[q] + fb[q] + fd * w1rs[k0 + q], 0.f);
      ef[kt] = t;
    }
    const int rowb = wave * 32 + mt * 16 + fg * 4;
#pragma unroll
    for (int nt = 0; nt < 8; ++nt) {
      const int col = nt * 16 + fr;
      f32x4 acc = (f32x4){0.f, 0.f, 0.f, 0.f};
#pragma unroll
      for (int kt = 0; kt < 4; ++kt) {
        const h8 bfr = *reinterpret_cast<const h8*>(
            &mw2t[(size_t)col * 128 + kt * 32 + fg * 8]);
        acc = __builtin_amdgcn_mfma_f32_16x16x32_f16(ef[kt], bfr, acc, 0, 0, 0);
      }
#pragma unroll
      for (int r = 0; r < 4; ++r)
        Msh[(rowb + r) * 136 + col] = __builtin_bit_cast(u16, (_Float16)acc[r]);
    }
  }
  __syncthreads();

  // epilogue (round-5 verified layout): ty = node-in-block, tx = col-oct
  const int ty = tid >> 4, tx = tid & 15;
  const int node = i0 + ty;
  float xi_[8], ui_[8], mb2v[8], gwv[8];
  {
    bf8_to_f(&xin[(size_t)node * HDIM + tx * 8], xi_);
    bf8_to_f(&uu[(size_t)node * HDIM + tx * 8], ui_);
    const float4 m0 = *reinterpret_cast<const float4*>(&mb2[tx * 8]);
    const float4 m1 = *reinterpret_cast<const float4*>(&mb2[tx * 8 + 4]);
    mb2v[0] = m0.x; mb2v[1] = m0.y; mb2v[2] = m0.z; mb2v[3] = m0.w;
    mb2v[4] = m1.x; mb2v[5] = m1.y; mb2v[6] = m1.z; mb2v[7] = m1.w;
#pragma unroll
    for (int c = 0; c < 8; ++c) gwv[c] = gwrs[tx * 8 + c];
  }
  float msum[8];
#pragma unroll
  for (int c = 0; c < 8; ++c) msum[c] = 0.f;
#pragma unroll
  for (int r = 0; r < 8; ++r) {
    const int e = ty * 8 + r;
    const int j = jn[e];
    const float fd = fdv[e];
    float vj[8], xj[8];
    bf8_to_f(&vv[(size_t)j * HDIM + tx * 8], vj);
    bf8_to_f(&xin[(size_t)j * HDIM + tx * 8], xj);
    const h8 m8 = *reinterpret_cast<const h8*>(&Msh[e * 136 + tx * 8]);
#pragma unroll
    for (int c = 0; c < 8; ++c) {
      const float z = ui_[c] + vj[c] + fd * gwv[c];
      const float gsig = 1.f / (1.f + __expf(-z));
      const float M = (float)m8[c] + mb2v[c];
      msum[c] += gsig * M + (1.f - gsig) * xj[c];
    }
  }
  u32 w[4];
#pragma unroll
  for (int i = 0; i < 4; ++i) {
    float t0 = msum[2 * i] * 0.125f + xi_[2 * i];
    float t1 = msum[2 * i + 1] * 0.125f + xi_[2 * i + 1];
    t0 = (t0 > 0.f) ? t0 : NEG * t0;
    t1 = (t1 > 0.f) ? t1 : NEG * t1;
    w[i] = (u32)f2bf(t0) | ((u32)f2bf(t1) << 16);
  }
  *reinterpret_cast<uint4*>(&xout[(size_t)node * HDIM + tx * 8]) =
      make_uint4(w[0], w[1], w[2], w[3]);
}

// ---------------------------------------------------------------------------
// K4: per-graph max-pool over [x1|x2] (bf16), 2-layer head, log_softmax.
// ---------------------------------------------------------------------------
__global__ __launch_bounds__(256) void k_head(const u16* __restrict__ x1,
                                              const u16* __restrict__ x2,
                                              const float* __restrict__ cw1,
                                              const float* __restrict__ cb1,
                                              const float* __restrict__ cw2,
                                              const float* __restrict__ cb2,
                                              float* __restrict__ out) {
  __shared__ float xc[256];
  __shared__ float hid[128];
  __shared__ float red[128];
  const int b = blockIdx.x, t = threadIdx.x;
  const u16* src = (t < 128) ? x1 : x2;
  const int f = t & 127;
  const size_t base = (size_t)b * NPG;
  float m = -1e30f;
  for (int p = 0; p < NPG; p += 4) {
    const float v0 = bf2f(src[(base + p + 0) * HDIM + f]);
    const float v1 = bf2f(src[(base + p + 1) * HDIM + f]);
    const float v2 = bf2f(src[(base + p + 2) * HDIM + f]);
    const float v3 = bf2f(src[(base + p + 3) * HDIM + f]);
    m = fmaxf(m, fmaxf(fmaxf(v0, v1), fmaxf(v2, v3)));
  }
  xc[t] = m;
  __syncthreads();
  if (t < 128) {
    float acc = cb1[t];
    for (int f2 = 0; f2 < 256; ++f2) acc = fmaf(xc[f2], cw1[f2 * HDIM + t], acc);
    hid[t] = fmaxf(acc, 0.f);
  }
  __syncthreads();
  if (t < 128) red[t] = hid[t] * cw2[t * 2 + 0];
  __syncthreads();
  for (int s = 64; s > 0; s >>= 1) {
    if (t < s) red[t] += red[t + s];
    __syncthreads();
  }
  float l0 = 0.f;
  if (t == 0) l0 = red[0] + cb2[0];
  __syncthreads();
  if (t < 128) red[t] = hid[t] * cw2[t * 2 + 1];
  __syncthreads();
  for (int s = 64; s > 0; s >>= 1) {
    if (t < s) red[t] += red[t + s];
    __syncthreads();
  }
  if (t == 0) {
    const float l1 = red[0] + cb2[1];
    const float mm = fmaxf(l0, l1);
    const float lse = mm + logf(__expf(l0 - mm) + __expf(l1 - mm));
    out[b * 2 + 0] = l0 - lse;
    out[b * 2 + 1] = l1 - lse;
  }
}

// ---------------------------------------------------------------------------
extern "C" void kernel_launch(void* const* d_in, const int* in_sizes, int n_in,
                              void* d_out, int out_size, void* d_ws, size_t ws_size,
                              hipStream_t stream) {
  (void)in_sizes; (void)n_in; (void)out_size; (void)ws_size;
  const float* x      = (const float*)d_in[0];
  const float* w0     = (const float*)d_in[2];
  const float* b0     = (const float*)d_in[3];
  const float* c1_mw1 = (const float*)d_in[4];
  const float* c1_mb1 = (const float*)d_in[5];
  const float* c1_mw2 = (const float*)d_in[6];
  const float* c1_mb2 = (const float*)d_in[7];
  const float* c1_gw  = (const float*)d_in[8];
  const float* c1_gb  = (const float*)d_in[9];
  const float* c2_mw1 = (const float*)d_in[10];
  const float* c2_mb1 = (const float*)d_in[11];
  const float* c2_mw2 = (const float*)d_in[12];
  const float* c2_mb2 = (const float*)d_in[13];
  const float* c2_gw  = (const float*)d_in[14];
  const float* c2_gb  = (const float*)d_in[15];
  const float* cw1    = (const float*)d_in[16];
  const float* cb1    = (const float*)d_in[17];
  const float* cw2    = (const float*)d_in[18];
  const float* cb2    = (const float*)d_in[19];

  const size_t NF = (size_t)NTOT * HDIM;  // 8388608 elements
  u16* wsh   = (u16*)d_ws;
  u16* xh_hi = wsh + 0 * NF;
  u16* xh_lo = wsh + 1 * NF;
  u16* x1b   = wsh + 2 * NF;
  u16* x2b   = wsh + 3 * NF;
  u16* a1v   = wsh + 4 * NF;
  u16* a2v   = wsh + 5 * NF;
  u16* uv    = wsh + 6 * NF;
  u16* vv_   = wsh + 7 * NF;
  u16* Wt    = wsh + 8 * NF;                      // 10 * 128*128 u16
  float* sqv = (float*)(Wt + 10 * 128 * 128);     // NTOT fp32
  int* nbrv  = (int*)(sqv + NTOT);                // NTOT*8 int
  // total ~137 MB

  k_prep<<<10, 256, 0, stream>>>(c1_mw1, c1_gw, c2_mw1, c2_gw, c1_mw2, c2_mw2, Wt);
  k_embed<<<2048, 256, 0, stream>>>(x, w0, b0, xh_hi, xh_lo, sqv);
  k_knn<<<512, 256, 0, stream>>>(xh_hi, xh_lo, sqv, nbrv);

  k_ng<<<dim3(512, 4), 256, 0, stream>>>(xh_hi, Wt, c1_mb1, c1_gb,
                                         a1v, a2v, uv, vv_);
  k_conv<<<4096, 256, 0, stream>>>(xh_hi, nbrv, x, a1v, a2v, uv, vv_,
                                   c1_mw1, Wt + 8 * 128 * 128, c1_mb2, c1_gw, x1b);

  k_ng<<<dim3(512, 4), 256, 0, stream>>>(x1b, Wt + 4 * 128 * 128, c2_mb1, c2_gb,
                                         a1v, a2v, uv, vv_);
  k_conv<<<4096, 256, 0, stream>>>(x1b, nbrv, x, a1v, a2v, uv, vv_,
                                   c2_mw1, Wt + 9 * 128 * 128, c2_mb2, c2_gw, x2b);

  k_head<<<64, 256, 0, stream>>>(x1b, x2b, cw1, cb1, cw2, cb2, (float*)d_out);
}

// Round 14
// 639.293 us; speedup vs baseline: 1.2236x; 1.2236x over previous
//
#include <hip/hip_runtime.h>
#include <math.h>
#include <stdint.h>

// Problem constants
#define NTOT   65536
#define NPG    1024
#define KNN    8
#define HDIM   128
#define XSTR   33     // x row stride (32 feat + 1 kf)
#define NEG    0.2f

typedef _Float16 h2 __attribute__((ext_vector_type(2)));
typedef _Float16 h8 __attribute__((ext_vector_type(8)));   // f16x8 MFMA frag
typedef short bf16x8 __attribute__((ext_vector_type(8)));
typedef float f32x4 __attribute__((ext_vector_type(4)));
typedef unsigned short u16;
typedef unsigned int u32;

__device__ __forceinline__ u16 f2bf(float f) {  // RNE float->bf16
  const u32 u = __builtin_bit_cast(u32, f);
  return (u16)((u + 0x7FFFu + ((u >> 16) & 1u)) >> 16);
}
__device__ __forceinline__ float bf2f(u16 h) {
  return __builtin_bit_cast(float, ((u32)h) << 16);
}
__device__ __forceinline__ void bf8_to_f(const u16* __restrict__ p, float* f) {
  const uint4 v = *reinterpret_cast<const uint4*>(p);
  const u32 w[4] = {v.x, v.y, v.z, v.w};
#pragma unroll
  for (int i = 0; i < 4; ++i) {
    f[2 * i]     = bf2f((u16)(w[i] & 0xffffu));
    f[2 * i + 1] = bf2f((u16)(w[i] >> 16));
  }
}

// ---------------------------------------------------------------------------
// K0: xh = relu(feat @ w0 + b0) -> split bf16 (hi, lo); sq[n] = sum(xh^2) fp32
// ---------------------------------------------------------------------------
__global__ __launch_bounds__(256) void k_embed(const float* __restrict__ x,
                                               const float* __restrict__ w0,
                                               const float* __restrict__ b0,
                                               u16* __restrict__ xh_hi,
                                               u16* __restrict__ xh_lo,
                                               float* __restrict__ sq) {
  __shared__ float w0s[32 * HDIM];
  __shared__ float fs[2][32];
  __shared__ float red[256];
  const int tid = threadIdx.x;
  for (int i = tid; i < 32 * HDIM; i += 256) w0s[i] = w0[i];
  const int h = tid & 127;
  const int nl = tid >> 7;
  const float bias = b0[h];
  for (int it = 0; it < 16; ++it) {
    const int n = blockIdx.x * 32 + it * 2 + nl;
    __syncthreads();
    if (tid < 64) {
      const int r = tid >> 5, f = tid & 31;
      fs[r][f] = x[(size_t)(blockIdx.x * 32 + it * 2 + r) * XSTR + f];
    }
    __syncthreads();
    float acc = bias;
#pragma unroll
    for (int f = 0; f < 32; ++f) acc = fmaf(fs[nl][f], w0s[f * HDIM + h], acc);
    acc = fmaxf(acc, 0.f);
    const u16 hh = f2bf(acc);
    xh_hi[(size_t)n * HDIM + h] = hh;
    xh_lo[(size_t)n * HDIM + h] = f2bf(acc - bf2f(hh));
    red[tid] = acc * acc;
    __syncthreads();
    for (int s = 64; s > 0; s >>= 1) {
      if ((tid & 127) < s) red[tid] += red[tid + s];
      __syncthreads();
    }
    if ((tid & 127) == 0) sq[n] = red[tid];
  }
}

// ---------------------------------------------------------------------------
// K-prep: b 0..7: transpose node-GEMM weight blocks to bf16 [n][k].
//          b 8..9: transpose mw2 (layer 1/2) to f16 [h][k].
// grid 10 x 256.
// ---------------------------------------------------------------------------
__global__ __launch_bounds__(256) void k_prep(const float* __restrict__ m1,
                                              const float* __restrict__ g1,
                                              const float* __restrict__ m2,
                                              const float* __restrict__ g2,
                                              const float* __restrict__ w2a,
                                              const float* __restrict__ w2b,
                                              u16* __restrict__ Wt) {
  const int b = blockIdx.x;
  const int t = threadIdx.x;
  const int n = t >> 1, k0 = (t & 1) * 64;
  u16* dst = Wt + (size_t)b * 128 * 128;
  if (b < 8) {
    const int layer = b >> 2, which = b & 3;
    const float* src = (layer == 0) ? ((which < 2) ? m1 : g1)
                                    : ((which < 2) ? m2 : g2);
    src += (size_t)(which & 1) * 128 * HDIM;
    for (int kk = 0; kk < 64; kk += 2) {
      const float f0 = src[(size_t)(k0 + kk) * HDIM + n];
      const float f1 = src[(size_t)(k0 + kk + 1) * HDIM + n];
      const u32 pk = (u32)f2bf(f0) | ((u32)f2bf(f1) << 16);
      *reinterpret_cast<u32*>(&dst[(size_t)n * 128 + k0 + kk]) = pk;
    }
  } else {
    const float* src = (b == 8) ? w2a : w2b;
    for (int kk = 0; kk < 64; kk += 2) {
      const float f0 = src[(size_t)(k0 + kk) * HDIM + n];
      const float f1 = src[(size_t)(k0 + kk + 1) * HDIM + n];
      const u16 h0 = __builtin_bit_cast(u16, (_Float16)f0);
      const u16 h1 = __builtin_bit_cast(u16, (_Float16)f1);
      const u32 pk = (u32)h0 | ((u32)h1 << 16);
      *reinterpret_cast<u32*>(&dst[(size_t)n * 128 + k0 + kk]) = pk;
    }
  }
}

// ---------------------------------------------------------------------------
// K1: per-graph kNN via split-bf16 MFMA (hi*hi + hi*lo + lo*hi, fp32 accum).
// grid 512 (64 graphs x 8 row-blocks of 128), 256 threads = 4 waves.
// ---------------------------------------------------------------------------
__global__ __launch_bounds__(256) void k_knn(const u16* __restrict__ xh_hi,
                                             const u16* __restrict__ xh_lo,
                                             const float* __restrict__ sq,
                                             int* __restrict__ nbr) {
  __shared__ __align__(16) u16 BsH[32 * 128];
  __shared__ __align__(16) u16 BsL[32 * 128];
  __shared__ __align__(16) float Ds[128 * 33];
  __shared__ float sqs[32];
  const int tid = threadIdx.x;
  const int wave = tid >> 6, lane = tid & 63;
  const int fr = lane & 15, fg = lane >> 4;
  const int g = blockIdx.x >> 3;
  const int n0 = (blockIdx.x & 7) * 128;
  const int gbase = g * NPG;

  bf16x8 aH[2][4], aL[2][4];
#pragma unroll
  for (int mt = 0; mt < 2; ++mt)
#pragma unroll
    for (int kt = 0; kt < 4; ++kt) {
      const size_t off =
          (size_t)(gbase + n0 + wave * 32 + mt * 16 + fr) * HDIM + kt * 32 + fg * 8;
      aH[mt][kt] = *reinterpret_cast<const bf16x8*>(&xh_hi[off]);
      aL[mt][kt] = *reinterpret_cast<const bf16x8*>(&xh_lo[off]);
    }

  const int srow = tid >> 1, shalf = tid & 1;
  const int nglob = gbase + n0 + srow;
  float bd[8];
  int bi[8];
#pragma unroll
  for (int i = 0; i < 8; ++i) { bd[i] = 1e30f; bi[i] = 0; }

  char* BsHc = reinterpret_cast<char*>(BsH);
  char* BsLc = reinterpret_cast<char*>(BsL);

  for (int ct = 0; ct < 32; ++ct) {
    const int m0 = gbase + ct * 32;
    __syncthreads();
    if (tid < 32) sqs[tid] = sq[m0 + tid];
    {
      const int col = tid >> 3, kc = (tid & 7) * 16;
      const size_t off = (size_t)(m0 + col) * HDIM + kc;
      const uint4 h0 = *reinterpret_cast<const uint4*>(&xh_hi[off]);
      const uint4 h1 = *reinterpret_cast<const uint4*>(&xh_hi[off + 8]);
      const uint4 l0 = *reinterpret_cast<const uint4*>(&xh_lo[off]);
      const uint4 l1 = *reinterpret_cast<const uint4*>(&xh_lo[off + 8]);
      const int base = col * 256, sw = (col & 7) << 4;
      const int kb = kc * 2;
      *reinterpret_cast<uint4*>(BsHc + base + ((kb) ^ sw)) = h0;
      *reinterpret_cast<uint4*>(BsHc + base + ((kb + 16) ^ sw)) = h1;
      *reinterpret_cast<uint4*>(BsLc + base + ((kb) ^ sw)) = l0;
      *reinterpret_cast<uint4*>(BsLc + base + ((kb + 16) ^ sw)) = l1;
    }
    __syncthreads();
    f32x4 acc[2][2];
#pragma unroll
    for (int mt = 0; mt < 2; ++mt)
#pragma unroll
      for (int nt = 0; nt < 2; ++nt) acc[mt][nt] = (f32x4){0.f, 0.f, 0.f, 0.f};
#pragma unroll
    for (int nt = 0; nt < 2; ++nt) {
      bf16x8 bH[4], bL[4];
      const int col = nt * 16 + fr;
      const int base = col * 256, sw = (col & 7) << 4;
#pragma unroll
      for (int kt = 0; kt < 4; ++kt) {
        const int kb = (kt * 32 + fg * 8) * 2;
        bH[kt] = *reinterpret_cast<const bf16x8*>(BsHc + base + (kb ^ sw));
        bL[kt] = *reinterpret_cast<const bf16x8*>(BsLc + base + (kb ^ sw));
      }
#pragma unroll
      for (int mt = 0; mt < 2; ++mt)
#pragma unroll
        for (int kt = 0; kt < 4; ++kt) {
          acc[mt][nt] = __builtin_amdgcn_mfma_f32_16x16x32_bf16(
              aH[mt][kt], bH[kt], acc[mt][nt], 0, 0, 0);
          acc[mt][nt] = __builtin_amdgcn_mfma_f32_16x16x32_bf16(
              aH[mt][kt], bL[kt], acc[mt][nt], 0, 0, 0);
          acc[mt][nt] = __builtin_amdgcn_mfma_f32_16x16x32_bf16(
              aL[mt][kt], bH[kt], acc[mt][nt], 0, 0, 0);
        }
    }
#pragma unroll
    for (int mt = 0; mt < 2; ++mt)
#pragma unroll
      for (int nt = 0; nt < 2; ++nt)
#pragma unroll
        for (int r = 0; r < 4; ++r)
          Ds[(wave * 32 + mt * 16 + fg * 4 + r) * 33 + nt * 16 + fr] =
              acc[mt][nt][r];
    __syncthreads();
#pragma unroll
    for (int c2 = 0; c2 < 16; ++c2) {
      const int c = shalf * 16 + c2;
      const int m = m0 + c;
      const float d = sqs[c] - 2.f * Ds[srow * 33 + c];
      if ((m != nglob) && (d < bd[7])) {
        bd[7] = d; bi[7] = m;
#pragma unroll
        for (int q = 7; q > 0; --q) {
          if (bd[q] < bd[q - 1]) {
            const float td = bd[q]; bd[q] = bd[q - 1]; bd[q - 1] = td;
            const int ti = bi[q]; bi[q] = bi[q - 1]; bi[q - 1] = ti;
          }
        }
      }
    }
  }
  __syncthreads();
  float* mdist = Ds;
  int* midx = reinterpret_cast<int*>(BsH);
#pragma unroll
  for (int i = 0; i < 8; ++i) { mdist[tid * 8 + i] = bd[i]; midx[tid * 8 + i] = bi[i]; }
  __syncthreads();
  if (shalf == 0) {
    const float* dA = &mdist[(srow * 2) * 8];
    const float* dB = &mdist[(srow * 2 + 1) * 8];
    const int* iA = &midx[(srow * 2) * 8];
    const int* iB = &midx[(srow * 2 + 1) * 8];
    int pa = 0, pb = 0;
    int* outp = &nbr[(size_t)nglob * KNN];
#pragma unroll
    for (int i = 0; i < 8; ++i) {
      const float da = dA[pa], db = dB[pb];
      const bool takeA = (da < db) || ((da == db) && (iA[pa] < iB[pb]));
      outp[i] = takeA ? iA[pa] : iB[pb];
      if (takeA) ++pa; else ++pb;
    }
  }
}

// ---------------------------------------------------------------------------
// K2: node GEMMs via bf16 MFMA. out = xin_b @ W (+bias) -> bf16.
// ---------------------------------------------------------------------------
__global__ __launch_bounds__(256) void k_ng(const u16* __restrict__ xin_b,
                                            const u16* __restrict__ WtL,
                                            const float* __restrict__ mb1,
                                            const float* __restrict__ gb,
                                            u16* __restrict__ a1,
                                            u16* __restrict__ a2,
                                            u16* __restrict__ uu,
                                            u16* __restrict__ vv) {
  const int tid = threadIdx.x;
  const int wave = tid >> 6, lane = tid & 63;
  const int fr = lane & 15, fg = lane >> 4;
  const int n0 = blockIdx.x * 128;
  const int cb = blockIdx.y;
  const u16* W = WtL + (size_t)cb * 128 * 128;
  const float* bias = (cb == 0) ? mb1 : (cb == 2) ? gb : nullptr;
  u16* outp = (cb == 0) ? a1 : (cb == 1) ? a2 : (cb == 2) ? uu : vv;

  bf16x8 afr[2][4];
#pragma unroll
  for (int mt = 0; mt < 2; ++mt)
#pragma unroll
    for (int kt = 0; kt < 4; ++kt)
      afr[mt][kt] = *reinterpret_cast<const bf16x8*>(
          &xin_b[(size_t)(n0 + wave * 32 + mt * 16 + fr) * HDIM + kt * 32 + fg * 8]);

#pragma unroll
  for (int nt = 0; nt < 8; ++nt) {
    const int col = nt * 16 + fr;
    bf16x8 bfr[4];
#pragma unroll
    for (int kt = 0; kt < 4; ++kt)
      bfr[kt] = *reinterpret_cast<const bf16x8*>(&W[(size_t)col * 128 + kt * 32 + fg * 8]);
    const float bv = bias ? bias[col] : 0.f;
#pragma unroll
    for (int mt = 0; mt < 2; ++mt) {
      f32x4 acc = (f32x4){0.f, 0.f, 0.f, 0.f};
#pragma unroll
      for (int kt = 0; kt < 4; ++kt)
        acc = __builtin_amdgcn_mfma_f32_16x16x32_bf16(afr[mt][kt], bfr[kt], acc, 0, 0, 0);
      const int rbase = n0 + wave * 32 + mt * 16 + fg * 4;
#pragma unroll
      for (int r = 0; r < 4; ++r)
        outp[(size_t)(rbase + r) * HDIM + col] = f2bf(acc[r] + bv);
    }
  }
}

// ---------------------------------------------------------------------------
// K3: fused highway edge conv — R8 issue order + low liveness.
// All 8 E-fragments built upfront (16 independent gathers in flight = deep
// MLP, the R8 property that made it fastest); nt-outer GEMM with per-nt f16
// LDS staging (only 8 acc VGPRs live; 32 B-loads total). Plain
// __launch_bounds__(256): R9's (256,4) hint clamped to 64 VGPR and spilled
// (WRITE_SIZE 16->224 MB); R10's mt-outer halved gather MLP and was slower
// than R8 despite 3x occupancy. LDS: f16 Msh = 34.8 KB -> 4 blocks/CU.
// grid 4096 x 256 (4 waves).
// ---------------------------------------------------------------------------
__global__ __launch_bounds__(256) void k_conv(const u16* __restrict__ xin,
                                              const int* __restrict__ nbr,
                                              const float* __restrict__ xraw,
                                              const u16* __restrict__ a1,
                                              const u16* __restrict__ a2,
                                              const u16* __restrict__ uu,
                                              const u16* __restrict__ vv,
                                              const float* __restrict__ mw1,
                                              const u16* __restrict__ mw2t,  // f16 [h][k]
                                              const float* __restrict__ mb2,
                                              const float* __restrict__ gw,
                                              u16* __restrict__ xout) {
  __shared__ __align__(16) u16 Msh[128 * 136];   // f16 M, 34816 B
  __shared__ int jn[128];
  __shared__ float fdv[128];
  __shared__ float w1rs[HDIM];
  __shared__ float gwrs[HDIM];
  const int tid = threadIdx.x;
  const int i0 = blockIdx.x * 16;

  if (tid < 128) {
    w1rs[tid] = mw1[256 * HDIM + tid];
    gwrs[tid] = gw[256 * HDIM + tid];
    const int i = i0 + (tid >> 3);
    const int j = nbr[(size_t)i * KNN + (tid & 7)];
    jn[tid] = j;
    fdv[tid] = xraw[(size_t)i * XSTR + 32] - xraw[(size_t)j * XSTR + 32];
  }
  __syncthreads();

  const int wave = tid >> 6, lane = tid & 63;
  const int fr = lane & 15, fg = lane >> 4;

  // Build ALL E fragments upfront (R8 issue order: 16 gathers in flight).
  h8 efrag[2][4];
#pragma unroll
  for (int mt = 0; mt < 2; ++mt) {
    const int e = wave * 32 + mt * 16 + fr;
    const int inode = i0 + (e >> 3);
    const int j = jn[e];
    const float fd = fdv[e];
#pragma unroll
    for (int kt = 0; kt < 4; ++kt) {
      const int k0 = kt * 32 + fg * 8;
      float fa[8], fb[8];
      bf8_to_f(&a1[(size_t)inode * HDIM + k0], fa);
      bf8_to_f(&a2[(size_t)j * HDIM + k0], fb);
      h8 ef;
#pragma unroll
      for (int q = 0; q < 8; ++q)
        ef[q] = (_Float16)fmaxf(fa[q] + fb[q] + fd * w1rs[k0 + q], 0.f);
      efrag[mt][kt] = ef;
    }
  }

  // nt-outer GEMM, staging each acc to f16 LDS immediately (low liveness).
#pragma unroll
  for (int nt = 0; nt < 8; ++nt) {
    const int col = nt * 16 + fr;
    h8 bfr[4];
#pragma unroll
    for (int kt = 0; kt < 4; ++kt)
      bfr[kt] = *reinterpret_cast<const h8*>(&mw2t[(size_t)col * 128 + kt * 32 + fg * 8]);
#pragma unroll
    for (int mt = 0; mt < 2; ++mt) {
      f32x4 acc = (f32x4){0.f, 0.f, 0.f, 0.f};
#pragma unroll
      for (int kt = 0; kt < 4; ++kt)
        acc = __builtin_amdgcn_mfma_f32_16x16x32_f16(efrag[mt][kt], bfr[kt], acc, 0, 0, 0);
      const int rowb = wave * 32 + mt * 16 + fg * 4;
#pragma unroll
      for (int r = 0; r < 4; ++r)
        Msh[(rowb + r) * 136 + col] = __builtin_bit_cast(u16, (_Float16)acc[r]);
    }
  }
  __syncthreads();

  // epilogue (round-5 verified layout): ty = node-in-block, tx = col-oct
  const int ty = tid >> 4, tx = tid & 15;
  const int node = i0 + ty;
  float xi_[8], ui_[8], mb2v[8], gwv[8];
  {
    bf8_to_f(&xin[(size_t)node * HDIM + tx * 8], xi_);
    bf8_to_f(&uu[(size_t)node * HDIM + tx * 8], ui_);
    const float4 m0 = *reinterpret_cast<const float4*>(&mb2[tx * 8]);
    const float4 m1 = *reinterpret_cast<const float4*>(&mb2[tx * 8 + 4]);
    mb2v[0] = m0.x; mb2v[1] = m0.y; mb2v[2] = m0.z; mb2v[3] = m0.w;
    mb2v[4] = m1.x; mb2v[5] = m1.y; mb2v[6] = m1.z; mb2v[7] = m1.w;
#pragma unroll
    for (int c = 0; c < 8; ++c) gwv[c] = gwrs[tx * 8 + c];
  }
  float msum[8];
#pragma unroll
  for (int c = 0; c < 8; ++c) msum[c] = 0.f;
#pragma unroll
  for (int r = 0; r < 8; ++r) {
    const int e = ty * 8 + r;
    const int j = jn[e];
    const float fd = fdv[e];
    float vj[8], xj[8];
    bf8_to_f(&vv[(size_t)j * HDIM + tx * 8], vj);
    bf8_to_f(&xin[(size_t)j * HDIM + tx * 8], xj);
    const h8 m8 = *reinterpret_cast<const h8*>(&Msh[e * 136 + tx * 8]);
#pragma unroll
    for (int c = 0; c < 8; ++c) {
      const float z = ui_[c] + vj[c] + fd * gwv[c];
      const float gsig = 1.f / (1.f + __expf(-z));
      const float M = (float)m8[c] + mb2v[c];
      msum[c] += gsig * M + (1.f - gsig) * xj[c];
    }
  }
  u32 w[4];
#pragma unroll
  for (int i = 0; i < 4; ++i) {
    float t0 = msum[2 * i] * 0.125f + xi_[2 * i];
    float t1 = msum[2 * i + 1] * 0.125f + xi_[2 * i + 1];
    t0 = (t0 > 0.f) ? t0 : NEG * t0;
    t1 = (t1 > 0.f) ? t1 : NEG * t1;
    w[i] = (u32)f2bf(t0) | ((u32)f2bf(t1) << 16);
  }
  *reinterpret_cast<uint4*>(&xout[(size_t)node * HDIM + tx * 8]) =
      make_uint4(w[0], w[1], w[2], w[3]);
}

// ---------------------------------------------------------------------------
// K4: per-graph max-pool over [x1|x2] (bf16), 2-layer head, log_softmax.
// ---------------------------------------------------------------------------
__global__ __launch_bounds__(256) void k_head(const u16* __restrict__ x1,
                                              const u16* __restrict__ x2,
                                              const float* __restrict__ cw1,
                                              const float* __restrict__ cb1,
                                              const float* __restrict__ cw2,
                                              const float* __restrict__ cb2,
                                              float* __restrict__ out) {
  __shared__ float xc[256];
  __shared__ float hid[128];
  __shared__ float red[128];
  const int b = blockIdx.x, t = threadIdx.x;
  const u16* src = (t < 128) ? x1 : x2;
  const int f = t & 127;
  const size_t base = (size_t)b * NPG;
  float m = -1e30f;
  for (int p = 0; p < NPG; p += 4) {
    const float v0 = bf2f(src[(base + p + 0) * HDIM + f]);
    const float v1 = bf2f(src[(base + p + 1) * HDIM + f]);
    const float v2 = bf2f(src[(base + p + 2) * HDIM + f]);
    const float v3 = bf2f(src[(base + p + 3) * HDIM + f]);
    m = fmaxf(m, fmaxf(fmaxf(v0, v1), fmaxf(v2, v3)));
  }
  xc[t] = m;
  __syncthreads();
  if (t < 128) {
    float acc = cb1[t];
    for (int f2 = 0; f2 < 256; ++f2) acc = fmaf(xc[f2], cw1[f2 * HDIM + t], acc);
    hid[t] = fmaxf(acc, 0.f);
  }
  __syncthreads();
  if (t < 128) red[t] = hid[t] * cw2[t * 2 + 0];
  __syncthreads();
  for (int s = 64; s > 0; s >>= 1) {
    if (t < s) red[t] += red[t + s];
    __syncthreads();
  }
  float l0 = 0.f;
  if (t == 0) l0 = red[0] + cb2[0];
  __syncthreads();
  if (t < 128) red[t] = hid[t] * cw2[t * 2 + 1];
  __syncthreads();
  for (int s = 64; s > 0; s >>= 1) {
    if (t < s) red[t] += red[t + s];
    __syncthreads();
  }
  if (t == 0) {
    const float l1 = red[0] + cb2[1];
    const float mm = fmaxf(l0, l1);
    const float lse = mm + logf(__expf(l0 - mm) + __expf(l1 - mm));
    out[b * 2 + 0] = l0 - lse;
    out[b * 2 + 1] = l1 - lse;
  }
}

// ---------------------------------------------------------------------------
extern "C" void kernel_launch(void* const* d_in, const int* in_sizes, int n_in,
                              void* d_out, int out_size, void* d_ws, size_t ws_size,
                              hipStream_t stream) {
  (void)in_sizes; (void)n_in; (void)out_size; (void)ws_size;
  const float* x      = (const float*)d_in[0];
  const float* w0     = (const float*)d_in[2];
  const float* b0     = (const float*)d_in[3];
  const float* c1_mw1 = (const float*)d_in[4];
  const float* c1_mb1 = (const float*)d_in[5];
  const float* c1_mw2 = (const float*)d_in[6];
  const float* c1_mb2 = (const float*)d_in[7];
  const float* c1_gw  = (const float*)d_in[8];
  const float* c1_gb  = (const float*)d_in[9];
  const float* c2_mw1 = (const float*)d_in[10];
  const float* c2_mb1 = (const float*)d_in[11];
  const float* c2_mw2 = (const float*)d_in[12];
  const float* c2_mb2 = (const float*)d_in[13];
  const float* c2_gw  = (const float*)d_in[14];
  const float* c2_gb  = (const float*)d_in[15];
  const float* cw1    = (const float*)d_in[16];
  const float* cb1    = (const float*)d_in[17];
  const float* cw2    = (const float*)d_in[18];
  const float* cb2    = (const float*)d_in[19];

  const size_t NF = (size_t)NTOT * HDIM;  // 8388608 elements
  u16* wsh   = (u16*)d_ws;
  u16* xh_hi = wsh + 0 * NF;
  u16* xh_lo = wsh + 1 * NF;
  u16* x1b   = wsh + 2 * NF;
  u16* x2b   = wsh + 3 * NF;
  u16* a1v   = wsh + 4 * NF;
  u16* a2v   = wsh + 5 * NF;
  u16* uv    = wsh + 6 * NF;
  u16* vv_   = wsh + 7 * NF;
  u16* Wt    = wsh + 8 * NF;                      // 10 * 128*128 u16
  float* sqv = (float*)(Wt + 10 * 128 * 128);     // NTOT fp32
  int* nbrv  = (int*)(sqv + NTOT);                // NTOT*8 int
  // total ~137 MB

  k_prep<<<10, 256, 0, stream>>>(c1_mw1, c1_gw, c2_mw1, c2_gw, c1_mw2, c2_mw2, Wt);
  k_embed<<<2048, 256, 0, stream>>>(x, w0, b0, xh_hi, xh_lo, sqv);
  k_knn<<<512, 256, 0, stream>>>(xh_hi, xh_lo, sqv, nbrv);

  k_ng<<<dim3(512, 4), 256, 0, stream>>>(xh_hi, Wt, c1_mb1, c1_gb,
                                         a1v, a2v, uv, vv_);
  k_conv<<<4096, 256, 0, stream>>>(xh_hi, nbrv, x, a1v, a2v, uv, vv_,
                                   c1_mw1, Wt + 8 * 128 * 128, c1_mb2, c1_gw, x1b);

  k_ng<<<dim3(512, 4), 256, 0, stream>>>(x1b, Wt + 4 * 128 * 128, c2_mb1, c2_gb,
                                         a1v, a2v, uv, vv_);
  k_conv<<<4096, 256, 0, stream>>>(x1b, nbrv, x, a1v, a2v, uv, vv_,
                                   c2_mw1, Wt + 9 * 128 * 128, c2_mb2, c2_gw, x2b);

  k_head<<<64, 256, 0, stream>>>(x1b, x2b, cw1, cb1, cw2, cb2, (float*)d_out);
}